// Round 7
// baseline (212.059 us; speedup 1.0000x reference)
//
#include <hip/hip_runtime.h>

#define SC 20
#define EDIM 16
#define HDIM 10
#define NG 40          // 4*H
#define VOCAB 256
#define TROW 52        // padded ctab row stride (floats, multiple of 4 for b128)
#define SENT VOCAB     // sentinel zero row index

#if __has_builtin(__builtin_amdgcn_exp2f)
#define EXP2F(x) __builtin_amdgcn_exp2f(x)
#else
#define EXP2F(x) exp2f(x)
#endif
#if __has_builtin(__builtin_amdgcn_rcpf)
#define RCPF(x) __builtin_amdgcn_rcpf(x)
#else
#define RCPF(x) (1.0f / (x))
#endif

#define L2E 1.44269504088896340736f

__device__ __forceinline__ float fast_sig(float x) {
    return RCPF(1.0f + EXP2F(-x * L2E));
}
__device__ __forceinline__ float fast_tanh(float x) {
    float e = EXP2F(x * (2.0f * L2E));
    return 1.0f - 2.0f * RCPF(1.0f + e);
}
__device__ __forceinline__ void add4(float4& a, const float4 b) {
    a.x += b.x; a.y += b.y; a.z += b.z; a.w += b.w;
}
// acc[0..19] += x * {w0..w4}
__device__ __forceinline__ void fma20(float* acc, float x,
    float4 w0, float4 w1, float4 w2, float4 w3, float4 w4) {
    acc[0]  += x * w0.x; acc[1]  += x * w0.y; acc[2]  += x * w0.z; acc[3]  += x * w0.w;
    acc[4]  += x * w1.x; acc[5]  += x * w1.y; acc[6]  += x * w1.z; acc[7]  += x * w1.w;
    acc[8]  += x * w2.x; acc[9]  += x * w2.y; acc[10] += x * w2.z; acc[11] += x * w2.w;
    acc[12] += x * w3.x; acc[13] += x * w3.y; acc[14] += x * w3.z; acc[15] += x * w3.w;
    acc[16] += x * w4.x; acc[17] += x * w4.y; acc[18] += x * w4.z; acc[19] += x * w4.w;
}

// conv gather for one sequence into xv[0..11] (LDS, random-row broadcast-ish)
__device__ __forceinline__ void conv_gather(const float* ctab, int a0, int a1,
                                            int a2, int a3, float* xv) {
    const float4* r0 = (const float4*)(ctab + a0 * TROW);
    const float4* r1 = (const float4*)(ctab + a1 * TROW + 12);
    const float4* r2 = (const float4*)(ctab + a2 * TROW + 24);
    const float4* r3 = (const float4*)(ctab + a3 * TROW + 36);
    float4 C0 = r0[0], C1 = r0[1], C2 = r0[2];
    add4(C0, r1[0]); add4(C1, r1[1]); add4(C2, r1[2]);
    add4(C0, r2[0]); add4(C1, r2[1]); add4(C2, r2[2]);
    /* age-3 f0..3 block is all zeros -> skip */
    add4(C1, r3[1]); add4(C2, r3[2]);
    xv[0] = C0.x; xv[1] = C0.y; xv[2]  = C0.z; xv[3]  = C0.w;
    xv[4] = C1.x; xv[5] = C1.y; xv[6]  = C1.z; xv[7]  = C1.w;
    xv[8] = C2.x; xv[9] = C2.y; xv[10] = C2.z; xv[11] = C2.w;
}

// GEMV pass over 20 gate cols starting at float4-col `cof` (0 or 5).
// W rows stream from GLOBAL (uniform addr -> L1 broadcast), one row-pair
// lookahead hides L1 latency; sched_barrier bounds the in-flight window.
#define GEMV_PASS(za, cof)                                                    \
    {                                                                         \
        const float4* bg = (const float4*)Bv + (cof);                         \
        float4 b0 = bg[0], b1 = bg[1], b2 = bg[2], b3 = bg[3], b4 = bg[4];    \
        za[0]=b0.x;  za[1]=b0.y;  za[2]=b0.z;  za[3]=b0.w;                    \
        za[4]=b1.x;  za[5]=b1.y;  za[6]=b1.z;  za[7]=b1.w;                    \
        za[8]=b2.x;  za[9]=b2.y;  za[10]=b2.z; za[11]=b2.w;                   \
        za[12]=b3.x; za[13]=b3.y; za[14]=b3.z; za[15]=b3.w;                   \
        za[16]=b4.x; za[17]=b4.y; za[18]=b4.z; za[19]=b4.w;                   \
        float4 u0 = wg[(cof)], u1 = wg[(cof)+1], u2 = wg[(cof)+2],            \
               u3 = wg[(cof)+3], u4 = wg[(cof)+4];                            \
        float4 v0, v1, v2, v3, v4;                                            \
        _Pragma("unroll")                                                     \
        for (int dd = 0; dd < 11; ++dd) {                                     \
            const int d0 = 2 * dd, d1 = 2 * dd + 1;                           \
            v0 = wg[d1*10+(cof)];   v1 = wg[d1*10+(cof)+1];                   \
            v2 = wg[d1*10+(cof)+2]; v3 = wg[d1*10+(cof)+3];                   \
            v4 = wg[d1*10+(cof)+4];                                           \
            fma20(za, xv[d0], u0, u1, u2, u3, u4);                            \
            __builtin_amdgcn_sched_barrier(0);                                \
            if (dd < 10) {                                                    \
                u0 = wg[(d0+2)*10+(cof)];   u1 = wg[(d0+2)*10+(cof)+1];       \
                u2 = wg[(d0+2)*10+(cof)+2]; u3 = wg[(d0+2)*10+(cof)+3];       \
                u4 = wg[(d0+2)*10+(cof)+4];                                   \
            }                                                                 \
            fma20(za, xv[d1], v0, v1, v2, v3, v4);                            \
            __builtin_amdgcn_sched_barrier(0);                                \
        }                                                                     \
    }

__global__ __launch_bounds__(256, 1) void cnn_lstm_kernel(
    const int* __restrict__ inp, const float* __restrict__ emb,
    const float* __restrict__ k2, const float* __restrict__ k3,
    const float* __restrict__ k4,
    const float* __restrict__ wfw, const float* __restrict__ bfw,
    const float* __restrict__ wbw, const float* __restrict__ bbw,
    float* __restrict__ out)
{
    // ctab[v][age][f]: contribution of char v seen `age` steps ago to the 12
    // conv outputs at the current position. Row SENT is all zeros.
    __shared__ float ctab[(VOCAB + 1) * TROW];

    const int tid = threadIdx.x;

    // ---- build ctab: thread v = tid handles one vocab row ------------------
    {
        float er[EDIM];
        const float4* ep = (const float4*)(emb + tid * EDIM);
        float4 e0 = ep[0], e1 = ep[1], e2 = ep[2], e3 = ep[3];
        er[0] = e0.x; er[1] = e0.y; er[2] = e0.z; er[3] = e0.w;
        er[4] = e1.x; er[5] = e1.y; er[6] = e1.z; er[7] = e1.w;
        er[8] = e2.x; er[9] = e2.y; er[10] = e2.z; er[11] = e2.w;
        er[12] = e3.x; er[13] = e3.y; er[14] = e3.z; er[15] = e3.w;

        float* dst = ctab + tid * TROW;
        #pragma unroll
        for (int dlt = 0; dlt < 4; ++dlt) {
            float o[12];
            #pragma unroll
            for (int f = 0; f < 12; ++f) o[f] = 0.0f;
            const int tap2 = 1 - dlt, tap3 = 2 - dlt, tap4 = 3 - dlt;
            if (tap2 >= 0) {
                #pragma unroll
                for (int e = 0; e < EDIM; ++e) {
                    const float x = er[e];
                    #pragma unroll
                    for (int f = 0; f < 3; ++f) o[f] += x * k2[(tap2 * EDIM + e) * 3 + f];
                }
            }
            if (tap3 >= 0) {
                #pragma unroll
                for (int e = 0; e < EDIM; ++e) {
                    const float x = er[e];
                    #pragma unroll
                    for (int f = 0; f < 4; ++f) o[3 + f] += x * k3[(tap3 * EDIM + e) * 4 + f];
                }
            }
            {
                #pragma unroll
                for (int e = 0; e < EDIM; ++e) {
                    const float x = er[e];
                    #pragma unroll
                    for (int f = 0; f < 5; ++f) o[7 + f] += x * k4[(tap4 * EDIM + e) * 5 + f];
                }
            }
            #pragma unroll
            for (int f = 0; f < 12; ++f) dst[dlt * 12 + f] = o[f];
        }
    }
    if (tid < TROW) ctab[VOCAB * TROW + tid] = 0.0f;  // sentinel zero row
    __syncthreads();

    // ---- per-(sequence, direction) LSTM ------------------------------------
    const int dir = blockIdx.x >> 8;              // block-uniform
    const bool fw = (dir == 0);
    const int n = (blockIdx.x & 255) * 256 + tid;
    const int* inp_n = inp + n * SC;
    const float4* wg = (const float4*)(fw ? wfw : wbw); // W in GLOBAL (L1 broadcast)
    const float*  Bv = fw ? bfw : bbw;

    // xv = [conv feats (12), h (10)] — GEMV input vector, h kept in place
    float xv[22];
    float cs[HDIM];
    #pragma unroll
    for (int q = 0; q < HDIM; ++q) { xv[12 + q] = 0.0f; cs[q] = 0.0f; }

    // rolling chars at age 0..3 (a0 = current position's char)
    int a0, a1, a2, a3;
    if (fw) {
        a0 = inp_n[0]; a1 = SENT; a2 = SENT; a3 = SENT;
    } else {
        a0 = inp_n[SC - 1]; a1 = inp_n[SC - 2]; a2 = inp_n[SC - 3]; a3 = inp_n[SC - 4];
    }

    #pragma unroll 1
    for (int t = 0; t < SC; ++t) {
        // prefetch next char index at top; consumed at bottom of the body
        const int nidx = fw ? (t + 1) : (SC - 5 - t);
        int an = SENT;
        if ((t < SC - 1) && (nidx >= 0)) an = inp_n[nidx];

        // ---- conv gather (LDS) ---------------------------------------------
        conv_gather(ctab, a0, a1, a2, a3, xv);
        __builtin_amdgcn_sched_barrier(0);   // don't batch GEMV loads into conv

        // ---- pass 1: gate cols 0..19 (i, j) ---------------------------------
        float za[20];
        GEMV_PASS(za, 0)
        float ij[HDIM];
        #pragma unroll
        for (int q = 0; q < HDIM; ++q)
            ij[q] = fast_sig(za[q]) * fast_tanh(za[HDIM + q]);

        // ---- pass 2: gate cols 20..39 (f, o) --------------------------------
        float zb[20];
        GEMV_PASS(zb, 5)
        #pragma unroll
        for (int q = 0; q < HDIM; ++q) {
            const float fg = fast_sig(zb[q] + 1.0f);
            const float og = fast_sig(zb[HDIM + q]);
            cs[q] = fg * cs[q] + ij[q];
            xv[12 + q] = og * fast_tanh(cs[q]);
        }

        // ---- advance rolling char window -----------------------------------
        if (fw) { a3 = a2; a2 = a1; a1 = a0; a0 = an; }
        else    { a0 = a1; a1 = a2; a2 = a3; a3 = an; }
    }

    #pragma unroll
    for (int q = 0; q < HDIM; ++q)
        out[n * (2 * HDIM) + dir * HDIM + q] = xv[12 + q];
}

extern "C" void kernel_launch(void* const* d_in, const int* in_sizes, int n_in,
                              void* d_out, int out_size, void* d_ws, size_t ws_size,
                              hipStream_t stream) {
    const int*   inp = (const int*)d_in[0];
    const float* emb = (const float*)d_in[1];
    const float* k2  = (const float*)d_in[2];
    const float* k3  = (const float*)d_in[3];
    const float* k4  = (const float*)d_in[4];
    const float* wfw = (const float*)d_in[5];
    const float* bfw = (const float*)d_in[6];
    const float* wbw = (const float*)d_in[7];
    const float* bbw = (const float*)d_in[8];
    float* out = (float*)d_out;

    cnn_lstm_kernel<<<dim3(512), dim3(256), 0, stream>>>(
        inp, emb, k2, k3, k4, wfw, bfw, wbw, bbw, out);
}

// Round 8
// 65.844 us; speedup vs baseline: 3.2206x; 3.2206x over previous
//
#include <hip/hip_runtime.h>

#define SC 20
#define EDIM 16
#define HDIM 10
#define VOCAB 256
#define SENT VOCAB       // sentinel zero row
#define CROW 72          // ctab row stride in halves (144 B = 9*16 -> distinct bank quads)
#define WAVES 4

typedef _Float16 f16;
typedef __attribute__((ext_vector_type(2))) _Float16 f16x2;
typedef __attribute__((ext_vector_type(8))) _Float16 f16x8;
typedef __attribute__((ext_vector_type(4))) float f32x4;

#if __has_builtin(__builtin_amdgcn_exp2f)
#define EXP2F(x) __builtin_amdgcn_exp2f(x)
#else
#define EXP2F(x) exp2f(x)
#endif
#if __has_builtin(__builtin_amdgcn_rcpf)
#define RCPF(x) __builtin_amdgcn_rcpf(x)
#else
#define RCPF(x) (1.0f / (x))
#endif
#define L2E 1.44269504088896340736f

__device__ __forceinline__ float fast_sig(float x) {
    return RCPF(1.0f + EXP2F(-x * L2E));
}
__device__ __forceinline__ float fast_tanh(float x) {
    float e = EXP2F(x * (2.0f * L2E));
    return 1.0f - 2.0f * RCPF(1.0f + e);
}
__device__ __forceinline__ f16x2 bc2(unsigned u) { return __builtin_bit_cast(f16x2, u); }
__device__ __forceinline__ unsigned pk(float a, float b) {
    f16x2 t = {(f16)a, (f16)b};
    return __builtin_bit_cast(unsigned, t);
}

__global__ __launch_bounds__(256, 1) void cnn_lstm_kernel(
    const int* __restrict__ inp, const float* __restrict__ emb,
    const float* __restrict__ k2, const float* __restrict__ k3,
    const float* __restrict__ k4,
    const float* __restrict__ wfw, const float* __restrict__ bfw,
    const float* __restrict__ wbw, const float* __restrict__ bbw,
    float* __restrict__ out)
{
    // ctab[v]: 4 ages x 12 conv feats, fp16, each age at a 16-half boundary.
    __shared__ __align__(16) f16   ctab[(VOCAB + 1) * CROW];   // 37.0 KB
    // per-wave MFMA staging: X rows (seq-major, K=32 halves) and Z halves (20 f32)
    __shared__ __align__(16) f16   xbuf[WAVES][64][32];        // 16.4 KB
    __shared__ __align__(16) float zbuf[WAVES][64][20];        // 20.5 KB

    const int tid  = threadIdx.x;
    const int lane = tid & 63;
    const int w    = tid >> 6;
    const int g    = lane >> 4;      // k-group for MFMA frags
    const int c16  = lane & 15;      // col-within-tile / row-within-tile

    // ---- build ctab (fp16): thread v = tid handles one vocab row -----------
    {
        float er[EDIM];
        const float4* ep = (const float4*)(emb + tid * EDIM);
        float4 e0 = ep[0], e1 = ep[1], e2 = ep[2], e3 = ep[3];
        er[0] = e0.x; er[1] = e0.y; er[2] = e0.z; er[3] = e0.w;
        er[4] = e1.x; er[5] = e1.y; er[6] = e1.z; er[7] = e1.w;
        er[8] = e2.x; er[9] = e2.y; er[10] = e2.z; er[11] = e2.w;
        er[12] = e3.x; er[13] = e3.y; er[14] = e3.z; er[15] = e3.w;

        #pragma unroll
        for (int dlt = 0; dlt < 4; ++dlt) {
            float o[12];
            #pragma unroll
            for (int f = 0; f < 12; ++f) o[f] = 0.0f;
            const int tap2 = 1 - dlt, tap3 = 2 - dlt, tap4 = 3 - dlt;
            if (tap2 >= 0) {
                #pragma unroll
                for (int e = 0; e < EDIM; ++e) {
                    const float x = er[e];
                    #pragma unroll
                    for (int f = 0; f < 3; ++f) o[f] += x * k2[(tap2 * EDIM + e) * 3 + f];
                }
            }
            if (tap3 >= 0) {
                #pragma unroll
                for (int e = 0; e < EDIM; ++e) {
                    const float x = er[e];
                    #pragma unroll
                    for (int f = 0; f < 4; ++f) o[3 + f] += x * k3[(tap3 * EDIM + e) * 4 + f];
                }
            }
            {
                #pragma unroll
                for (int e = 0; e < EDIM; ++e) {
                    const float x = er[e];
                    #pragma unroll
                    for (int f = 0; f < 5; ++f) o[7 + f] += x * k4[(tap4 * EDIM + e) * 5 + f];
                }
            }
            f16* dst = &ctab[tid * CROW + 16 * dlt];
            uint4 s;
            s.x = pk(o[0], o[1]); s.y = pk(o[2], o[3]);
            s.z = pk(o[4], o[5]); s.w = pk(o[6], o[7]);
            *(uint4*)dst = s;
            *(uint2*)(dst + 8) = make_uint2(pk(o[8], o[9]), pk(o[10], o[11]));
        }
    }
    if (tid < 9) ((uint4*)&ctab[VOCAB * CROW])[tid] = make_uint4(0, 0, 0, 0);
    __syncthreads();

    // ---- per-(sequence, direction); wave = 64 seqs, MFMA per wave -----------
    const int dir = blockIdx.x >> 8;
    const bool fw = (dir == 0);
    const int n_seq = (blockIdx.x & 255) * 256 + tid;
    const int* inp_n = inp + n_seq * SC;
    const float* Wm = fw ? wfw : wbw;
    const float* Bv = fw ? bfw : bbw;

    // B-frags: W[k][col] fp16, k=8g+i; k==22 row carries the bias; k>22 zero.
    // Loaded ONCE — zero per-step weight traffic.
    f16x8 bfr[3];
    #pragma unroll
    for (int n = 0; n < 3; ++n) {
        #pragma unroll
        for (int i = 0; i < 8; ++i) {
            const int kk = 8 * g + i, col = 16 * n + c16;
            float val = 0.0f;
            if (col < 40) {
                if (kk < 22) val = Wm[kk * 40 + col];
                else if (kk == 22) val = Bv[col];
            }
            bfr[n][i] = (f16)val;
        }
    }

    // zero the K-pad of this lane's X row (halves 24..31) once; never rewritten
    *(uint4*)&xbuf[w][lane][24] = make_uint4(0, 0, 0, 0);

    float h[HDIM], cs[HDIM];
    #pragma unroll
    for (int q = 0; q < HDIM; ++q) { h[q] = 0.0f; cs[q] = 0.0f; }

    int a0, a1, a2, a3;
    if (fw) {
        a0 = inp_n[0]; a1 = SENT; a2 = SENT; a3 = SENT;
    } else {
        a0 = inp_n[SC - 1]; a1 = inp_n[SC - 2]; a2 = inp_n[SC - 3]; a3 = inp_n[SC - 4];
    }

    #pragma unroll 1
    for (int t = 0; t < SC; ++t) {
        const int nidx = fw ? (t + 1) : (SC - 5 - t);
        int an = SENT;
        if ((t < SC - 1) && (nidx >= 0)) an = inp_n[nidx];

        // ---- conv gather, fp16 packed adds ---------------------------------
        f16x2 xa0, xa1, xa2, xa3, xa4, xa5;
        {
            const f16* p = &ctab[a0 * CROW];
            uint4 P = *(const uint4*)p; uint2 Q = *(const uint2*)(p + 8);
            xa0 = bc2(P.x); xa1 = bc2(P.y); xa2 = bc2(P.z);
            xa3 = bc2(P.w); xa4 = bc2(Q.x); xa5 = bc2(Q.y);
        }
        {
            const f16* p = &ctab[a1 * CROW + 16];
            uint4 P = *(const uint4*)p; uint2 Q = *(const uint2*)(p + 8);
            xa0 += bc2(P.x); xa1 += bc2(P.y); xa2 += bc2(P.z);
            xa3 += bc2(P.w); xa4 += bc2(Q.x); xa5 += bc2(Q.y);
        }
        {
            const f16* p = &ctab[a2 * CROW + 32];
            uint4 P = *(const uint4*)p; uint2 Q = *(const uint2*)(p + 8);
            xa0 += bc2(P.x); xa1 += bc2(P.y); xa2 += bc2(P.z);
            xa3 += bc2(P.w); xa4 += bc2(Q.x); xa5 += bc2(Q.y);
        }
        {
            const f16* p = &ctab[a3 * CROW + 48];
            uint4 P = *(const uint4*)p; uint2 Q = *(const uint2*)(p + 8);
            xa0 += bc2(P.x); xa1 += bc2(P.y); xa2 += bc2(P.z);
            xa3 += bc2(P.w); xa4 += bc2(Q.x); xa5 += bc2(Q.y);
        }

        // ---- write X row: [x(12) | h(10) | 1.0 | 0]  (k-pad already zero) ---
        {
            uint4 W0, W1, W2;
            W0.x = __builtin_bit_cast(unsigned, xa0);
            W0.y = __builtin_bit_cast(unsigned, xa1);
            W0.z = __builtin_bit_cast(unsigned, xa2);
            W0.w = __builtin_bit_cast(unsigned, xa3);
            W1.x = __builtin_bit_cast(unsigned, xa4);
            W1.y = __builtin_bit_cast(unsigned, xa5);
            W1.z = pk(h[0], h[1]); W1.w = pk(h[2], h[3]);
            W2.x = pk(h[4], h[5]); W2.y = pk(h[6], h[7]);
            W2.z = pk(h[8], h[9]); W2.w = pk(1.0f, 0.0f);
            uint4* xrow = (uint4*)&xbuf[w][lane][0];
            xrow[0] = W0; xrow[1] = W1; xrow[2] = W2;
        }
        __builtin_amdgcn_sched_barrier(0);

        // ---- A-frags + 12 MFMAs (wave-private; same-wave LDS is in-order) ---
        f32x4 acc[4][3];
        const f32x4 zero4 = {0.0f, 0.0f, 0.0f, 0.0f};
        #pragma unroll
        for (int m = 0; m < 4; ++m) {
            f16x8 af = *(const f16x8*)&xbuf[w][16 * m + c16][8 * g];
            #pragma unroll
            for (int n = 0; n < 3; ++n)
                acc[m][n] = __builtin_amdgcn_mfma_f32_16x16x32_f16(af, bfr[n], zero4, 0, 0, 0);
        }
        __builtin_amdgcn_sched_barrier(0);

        // ---- pass 1: stage z cols 0..19, read own row, gates i,j -----------
        #pragma unroll
        for (int m = 0; m < 4; ++m)
            #pragma unroll
            for (int r = 0; r < 4; ++r)
                zbuf[w][16 * m + 4 * g + r][c16] = acc[m][0][r];
        if (c16 < 4) {
            #pragma unroll
            for (int m = 0; m < 4; ++m)
                #pragma unroll
                for (int r = 0; r < 4; ++r)
                    zbuf[w][16 * m + 4 * g + r][16 + c16] = acc[m][1][r];
        }
        __builtin_amdgcn_sched_barrier(0);
        float ij[HDIM];
        {
            const float4* zr = (const float4*)&zbuf[w][lane][0];
            float4 z0 = zr[0], z1 = zr[1], z2 = zr[2], z3 = zr[3], z4 = zr[4];
            float zz[20];
            zz[0]=z0.x; zz[1]=z0.y; zz[2]=z0.z; zz[3]=z0.w;
            zz[4]=z1.x; zz[5]=z1.y; zz[6]=z1.z; zz[7]=z1.w;
            zz[8]=z2.x; zz[9]=z2.y; zz[10]=z2.z; zz[11]=z2.w;
            zz[12]=z3.x; zz[13]=z3.y; zz[14]=z3.z; zz[15]=z3.w;
            zz[16]=z4.x; zz[17]=z4.y; zz[18]=z4.z; zz[19]=z4.w;
            #pragma unroll
            for (int q = 0; q < HDIM; ++q)
                ij[q] = fast_sig(zz[q]) * fast_tanh(zz[HDIM + q]);
        }
        __builtin_amdgcn_sched_barrier(0);

        // ---- pass 2: stage z cols 20..39, gates f,o; update c,h ------------
        if (c16 >= 4) {
            #pragma unroll
            for (int m = 0; m < 4; ++m)
                #pragma unroll
                for (int r = 0; r < 4; ++r)
                    zbuf[w][16 * m + 4 * g + r][c16 - 4] = acc[m][1][r];
        }
        if (c16 < 8) {
            #pragma unroll
            for (int m = 0; m < 4; ++m)
                #pragma unroll
                for (int r = 0; r < 4; ++r)
                    zbuf[w][16 * m + 4 * g + r][12 + c16] = acc[m][2][r];
        }
        __builtin_amdgcn_sched_barrier(0);
        {
            const float4* zr = (const float4*)&zbuf[w][lane][0];
            float4 z0 = zr[0], z1 = zr[1], z2 = zr[2], z3 = zr[3], z4 = zr[4];
            float zz[20];
            zz[0]=z0.x; zz[1]=z0.y; zz[2]=z0.z; zz[3]=z0.w;
            zz[4]=z1.x; zz[5]=z1.y; zz[6]=z1.z; zz[7]=z1.w;
            zz[8]=z2.x; zz[9]=z2.y; zz[10]=z2.z; zz[11]=z2.w;
            zz[12]=z3.x; zz[13]=z3.y; zz[14]=z3.z; zz[15]=z3.w;
            zz[16]=z4.x; zz[17]=z4.y; zz[18]=z4.z; zz[19]=z4.w;
            #pragma unroll
            for (int q = 0; q < HDIM; ++q) {
                const float fg = fast_sig(zz[q] + 1.0f);
                const float og = fast_sig(zz[HDIM + q]);
                cs[q] = fg * cs[q] + ij[q];
                h[q] = og * fast_tanh(cs[q]);
            }
        }
        __builtin_amdgcn_sched_barrier(0);

        if (fw) { a3 = a2; a2 = a1; a1 = a0; a0 = an; }
        else    { a0 = a1; a1 = a2; a2 = a3; a3 = an; }
    }

    #pragma unroll
    for (int q = 0; q < HDIM; ++q)
        out[n_seq * (2 * HDIM) + dir * HDIM + q] = h[q];
}

extern "C" void kernel_launch(void* const* d_in, const int* in_sizes, int n_in,
                              void* d_out, int out_size, void* d_ws, size_t ws_size,
                              hipStream_t stream) {
    const int*   inp = (const int*)d_in[0];
    const float* emb = (const float*)d_in[1];
    const float* k2  = (const float*)d_in[2];
    const float* k3  = (const float*)d_in[3];
    const float* k4  = (const float*)d_in[4];
    const float* wfw = (const float*)d_in[5];
    const float* bfw = (const float*)d_in[6];
    const float* wbw = (const float*)d_in[7];
    const float* bbw = (const float*)d_in[8];
    float* out = (float*)d_out;

    cnn_lstm_kernel<<<dim3(512), dim3(256), 0, stream>>>(
        inp, emb, k2, k3, k4, wfw, bfw, wbw, bbw, out);
}

// Round 9
// 58.765 us; speedup vs baseline: 3.6086x; 1.1205x over previous
//
#include <hip/hip_runtime.h>

#define SC 20
#define EDIM 16
#define HDIM 10
#define VOCAB 256
#define SENT VOCAB       // sentinel zero row
#define CROW 72          // ctab row stride in halves (144 B, 16B-aligned rows)
#define XROW 24          // xbuf row stride in halves (48 B): 12 x | 10 h | 1.0 | 0
#define WAVES 4

typedef _Float16 f16;
typedef __attribute__((ext_vector_type(2))) _Float16 f16x2;
typedef __attribute__((ext_vector_type(8))) _Float16 f16x8;
typedef __attribute__((ext_vector_type(4))) float f32x4;

#if __has_builtin(__builtin_amdgcn_exp2f)
#define EXP2F(x) __builtin_amdgcn_exp2f(x)
#else
#define EXP2F(x) exp2f(x)
#endif
#if __has_builtin(__builtin_amdgcn_rcpf)
#define RCPF(x) __builtin_amdgcn_rcpf(x)
#else
#define RCPF(x) (1.0f / (x))
#endif
#define L2E 1.44269504088896340736f

__device__ __forceinline__ float fast_sig(float x) {
    return RCPF(1.0f + EXP2F(-x * L2E));
}
__device__ __forceinline__ float fast_tanh(float x) {
    float e = EXP2F(x * (2.0f * L2E));
    return 1.0f - 2.0f * RCPF(1.0f + e);
}
__device__ __forceinline__ f16x2 bc2(unsigned u) { return __builtin_bit_cast(f16x2, u); }
__device__ __forceinline__ unsigned bcu(f16x2 v) { return __builtin_bit_cast(unsigned, v); }
__device__ __forceinline__ unsigned pk(float a, float b) {
    f16x2 t = {(f16)a, (f16)b};
    return __builtin_bit_cast(unsigned, t);
}

__global__ __launch_bounds__(256, 1) void cnn_lstm_kernel(
    const int* __restrict__ inp, const float* __restrict__ emb,
    const float* __restrict__ k2, const float* __restrict__ k3,
    const float* __restrict__ k4,
    const float* __restrict__ wfw, const float* __restrict__ bfw,
    const float* __restrict__ wbw, const float* __restrict__ bbw,
    float* __restrict__ out)
{
    // ctab[v]: 4 ages x 12 conv feats (fp16), each age at a 16-half boundary.
    __shared__ __align__(16) f16 ctab[(VOCAB + 1) * CROW];   // 37.0 KB
    // X rows per wave: [x(12) | h(10) | 1.0 | 0]; row 64 = junk-catcher for
    // the g=3 B-frag over-read (values are multiplied by zero A-rows anyway).
    __shared__ __align__(16) f16 xbuf[WAVES][65][XROW];      // 12.5 KB

    const int tid  = threadIdx.x;
    const int lane = tid & 63;
    const int w    = tid >> 6;
    const int g    = lane >> 4;
    const int c16  = lane & 15;

    // ---- build ctab (fp16): thread v = tid handles one vocab row -----------
    {
        float er[EDIM];
        const float4* ep = (const float4*)(emb + tid * EDIM);
        float4 e0 = ep[0], e1 = ep[1], e2 = ep[2], e3 = ep[3];
        er[0] = e0.x; er[1] = e0.y; er[2] = e0.z; er[3] = e0.w;
        er[4] = e1.x; er[5] = e1.y; er[6] = e1.z; er[7] = e1.w;
        er[8] = e2.x; er[9] = e2.y; er[10] = e2.z; er[11] = e2.w;
        er[12] = e3.x; er[13] = e3.y; er[14] = e3.z; er[15] = e3.w;

        #pragma unroll
        for (int dlt = 0; dlt < 4; ++dlt) {
            float o[12];
            #pragma unroll
            for (int f = 0; f < 12; ++f) o[f] = 0.0f;
            const int tap2 = 1 - dlt, tap3 = 2 - dlt, tap4 = 3 - dlt;
            if (tap2 >= 0) {
                #pragma unroll
                for (int e = 0; e < EDIM; ++e) {
                    const float x = er[e];
                    #pragma unroll
                    for (int f = 0; f < 3; ++f) o[f] += x * k2[(tap2 * EDIM + e) * 3 + f];
                }
            }
            if (tap3 >= 0) {
                #pragma unroll
                for (int e = 0; e < EDIM; ++e) {
                    const float x = er[e];
                    #pragma unroll
                    for (int f = 0; f < 4; ++f) o[3 + f] += x * k3[(tap3 * EDIM + e) * 4 + f];
                }
            }
            {
                #pragma unroll
                for (int e = 0; e < EDIM; ++e) {
                    const float x = er[e];
                    #pragma unroll
                    for (int f = 0; f < 5; ++f) o[7 + f] += x * k4[(tap4 * EDIM + e) * 5 + f];
                }
            }
            f16* dst = &ctab[tid * CROW + 16 * dlt];
            uint4 s;
            s.x = pk(o[0], o[1]); s.y = pk(o[2], o[3]);
            s.z = pk(o[4], o[5]); s.w = pk(o[6], o[7]);
            *(uint4*)dst = s;
            *(uint2*)(dst + 8) = make_uint2(pk(o[8], o[9]), pk(o[10], o[11]));
        }
    }
    if (tid < 9) ((uint4*)&ctab[VOCAB * CROW])[tid] = make_uint4(0, 0, 0, 0);
    __syncthreads();

    // ---- per-(sequence, direction); wave = 64 seqs ---------------------------
    const int dir   = blockIdx.x >> 8;
    const bool fw   = (dir == 0);
    const int nbase = (blockIdx.x & 255) * 256 + w * 64;   // wave's first seq
    const int n_seq = nbase + lane;                         // this lane's own seq
    const int* inp_n = inp + n_seq * SC;
    const float* Wm = fw ? wfw : wbw;
    const float* Bv = fw ? bfw : bbw;

    // A-frags: W_perm^T, loaded ONCE. Physical gate col G = 4Q + r carries
    // logical gate (r*10 + Q): r = part {i,j,f,o}, Q = quad = 4*mg + (c16>>2).
    // Rows k: 0..11 conv feats, 12..21 h, 22 bias, 23..31 zero pad.
    f16x8 afr[3];
    #pragma unroll
    for (int mg = 0; mg < 3; ++mg) {
        const int G = 16 * mg + c16;
        const int Q = G >> 2, r = G & 3;
        #pragma unroll
        for (int i = 0; i < 8; ++i) {
            const int kk = 8 * g + i;
            float val = 0.0f;
            if (Q < HDIM) {
                const int lcol = r * HDIM + Q;
                if (kk < 22) val = Wm[kk * 40 + lcol];
                else if (kk == 22) val = Bv[lcol];
            }
            afr[mg][i] = (f16)val;
        }
    }

    // init own X row: h = 0 (halves 12..21), bias-1.0 at half 22, 0 at 23
    {
        f16* xr = &xbuf[w][lane][0];
        *(uint2*)(xr + 12) = make_uint2(0u, 0u);
        *(uint2*)(xr + 16) = make_uint2(0u, 0u);
        *(unsigned*)(xr + 20) = 0u;
        *(unsigned*)(xr + 22) = pk(1.0f, 0.0f);
    }
    if (lane == 0) {   // zero the junk-catcher row (avoid NaN in over-reads)
        uint4* zr = (uint4*)&xbuf[w][64][0];
        zr[0] = make_uint4(0, 0, 0, 0);
        zr[1] = make_uint4(0, 0, 0, 0);
        zr[2] = make_uint4(0, 0, 0, 0);
    }

    // distributed LSTM state: lane (g,c16) owns quad Q=4*mg+g of seq 16*ms+c16
    float creg[4][3], hreg[4][3];
    #pragma unroll
    for (int ms = 0; ms < 4; ++ms)
        #pragma unroll
        for (int mg = 0; mg < 3; ++mg) { creg[ms][mg] = 0.0f; hreg[ms][mg] = 0.0f; }

    int a0, a1, a2, a3;
    if (fw) {
        a0 = inp_n[0]; a1 = SENT; a2 = SENT; a3 = SENT;
    } else {
        a0 = inp_n[SC - 1]; a1 = inp_n[SC - 2]; a2 = inp_n[SC - 3]; a3 = inp_n[SC - 4];
    }

    #pragma unroll 1
    for (int t = 0; t < SC; ++t) {
        const int nidx = fw ? (t + 1) : (SC - 5 - t);
        int an = SENT;
        if ((t < SC - 1) && (nidx >= 0)) an = inp_n[nidx];

        // ---- conv gather (fp16 packed adds) --------------------------------
        f16x2 xa0, xa1, xa2, xa3, xa4, xa5;
        {
            const f16* p = &ctab[a0 * CROW];
            uint4 P = *(const uint4*)p; uint2 Q = *(const uint2*)(p + 8);
            xa0 = bc2(P.x); xa1 = bc2(P.y); xa2 = bc2(P.z);
            xa3 = bc2(P.w); xa4 = bc2(Q.x); xa5 = bc2(Q.y);
        }
        {
            const f16* p = &ctab[a1 * CROW + 16];
            uint4 P = *(const uint4*)p; uint2 Q = *(const uint2*)(p + 8);
            xa0 += bc2(P.x); xa1 += bc2(P.y); xa2 += bc2(P.z);
            xa3 += bc2(P.w); xa4 += bc2(Q.x); xa5 += bc2(Q.y);
        }
        {
            const f16* p = &ctab[a2 * CROW + 32];
            uint4 P = *(const uint4*)p; uint2 Q = *(const uint2*)(p + 8);
            xa0 += bc2(P.x); xa1 += bc2(P.y); xa2 += bc2(P.z);
            xa3 += bc2(P.w); xa4 += bc2(Q.x); xa5 += bc2(Q.y);
        }
        {
            const f16* p = &ctab[a3 * CROW + 48];
            uint4 P = *(const uint4*)p; uint2 Q = *(const uint2*)(p + 8);
            xa0 += bc2(P.x); xa1 += bc2(P.y); xa2 += bc2(P.z);
            xa3 += bc2(P.w); xa4 += bc2(Q.x); xa5 += bc2(Q.y);
        }

        // ---- write x-part of own X row (h-part persists from last step) ----
        {
            f16* xr = &xbuf[w][lane][0];
            uint4 W0;
            W0.x = bcu(xa0); W0.y = bcu(xa1); W0.z = bcu(xa2); W0.w = bcu(xa3);
            *(uint4*)xr = W0;
            *(uint2*)(xr + 8) = make_uint2(bcu(xa4), bcu(xa5));
        }
        __builtin_amdgcn_sched_barrier(0);

        // ---- B-frags (X rows) + 12 MFMAs: Z^T tiles -------------------------
        f32x4 acc[4][3];
        const f32x4 zero4 = {0.0f, 0.0f, 0.0f, 0.0f};
        #pragma unroll
        for (int ms = 0; ms < 4; ++ms) {
            f16x8 bf = *(const f16x8*)&xbuf[w][16 * ms + c16][8 * g];
            #pragma unroll
            for (int mg = 0; mg < 3; ++mg)
                acc[ms][mg] = __builtin_amdgcn_mfma_f32_16x16x32_f16(afr[mg], bf, zero4, 0, 0, 0);
        }
        __builtin_amdgcn_sched_barrier(0);

        // ---- lane-local gate combine: acc[ms][mg] = (i,j,f,o) of (seq,Q) ---
        #pragma unroll
        for (int ms = 0; ms < 4; ++ms) {
            #pragma unroll
            for (int mg = 0; mg < 3; ++mg) {
                const f32x4 z = acc[ms][mg];
                const float ij = fast_sig(z[0]) * fast_tanh(z[1]);
                const float fg = fast_sig(z[2] + 1.0f);
                const float og = fast_sig(z[3]);
                const float cc = fg * creg[ms][mg] + ij;
                creg[ms][mg] = cc;
                const float hh = og * fast_tanh(cc);
                hreg[ms][mg] = hh;
                const int Q = 4 * mg + g;
                if (Q < HDIM)
                    xbuf[w][16 * ms + c16][12 + Q] = (f16)hh;
            }
        }
        __builtin_amdgcn_sched_barrier(0);

        if (fw) { a3 = a2; a2 = a1; a1 = a0; a0 = an; }
        else    { a0 = a1; a1 = a2; a2 = a3; a3 = an; }
    }

    // ---- output: lane owns quads Q=4*mg+g of seqs 16*ms+c16 -----------------
    #pragma unroll
    for (int ms = 0; ms < 4; ++ms) {
        #pragma unroll
        for (int mg = 0; mg < 3; ++mg) {
            const int Q = 4 * mg + g;
            if (Q < HDIM)
                out[(nbase + 16 * ms + c16) * (2 * HDIM) + dir * HDIM + Q] = hreg[ms][mg];
        }
    }
}

extern "C" void kernel_launch(void* const* d_in, const int* in_sizes, int n_in,
                              void* d_out, int out_size, void* d_ws, size_t ws_size,
                              hipStream_t stream) {
    const int*   inp = (const int*)d_in[0];
    const float* emb = (const float*)d_in[1];
    const float* k2  = (const float*)d_in[2];
    const float* k3  = (const float*)d_in[3];
    const float* k4  = (const float*)d_in[4];
    const float* wfw = (const float*)d_in[5];
    const float* bfw = (const float*)d_in[6];
    const float* wbw = (const float*)d_in[7];
    const float* bbw = (const float*)d_in[8];
    float* out = (float*)d_out;

    cnn_lstm_kernel<<<dim3(512), dim3(256), 0, stream>>>(
        inp, emb, k2, k3, k4, wfw, bfw, wbw, bbw, out);
}

// Round 10
// 57.413 us; speedup vs baseline: 3.6935x; 1.0235x over previous
//
#include <hip/hip_runtime.h>

#define SC 20
#define EDIM 16
#define HDIM 10
#define VOCAB 256
#define SENT VOCAB       // sentinel zero row
#define CROWH 56         // ctab row stride in halves (112 B, 16B-aligned, 8 bank classes)
#define XROW 24          // xbuf row stride in halves (48 B)
#define WAVES 4

typedef _Float16 f16;
typedef __attribute__((ext_vector_type(2))) _Float16 f16x2;
typedef __attribute__((ext_vector_type(8))) _Float16 f16x8;
typedef __attribute__((ext_vector_type(4))) float f32x4;

#if __has_builtin(__builtin_amdgcn_exp2f)
#define EXP2F(x) __builtin_amdgcn_exp2f(x)
#else
#define EXP2F(x) exp2f(x)
#endif
#if __has_builtin(__builtin_amdgcn_rcpf)
#define RCPF(x) __builtin_amdgcn_rcpf(x)
#else
#define RCPF(x) (1.0f / (x))
#endif
#define L2E 1.44269504088896340736f

__device__ __forceinline__ float fast_sig(float x) {
    return RCPF(1.0f + EXP2F(-x * L2E));
}
__device__ __forceinline__ float fast_tanh(float x) {
    float e = EXP2F(x * (2.0f * L2E));
    return 1.0f - 2.0f * RCPF(1.0f + e);
}
__device__ __forceinline__ f16x2 bc2(unsigned u) { return __builtin_bit_cast(f16x2, u); }
__device__ __forceinline__ unsigned bcu(f16x2 v) { return __builtin_bit_cast(unsigned, v); }
__device__ __forceinline__ unsigned pk(float a, float b) {
    f16x2 t = {(f16)a, (f16)b};
    return __builtin_bit_cast(unsigned, t);
}

// gather issue: 10 LDS reads (2xb128 + 8xb64) of 4 age-slices
#define G_ISSUE                                                         \
    {   const f16* q0 = &ctab[a0 * CROWH];                              \
        g0a = *(const uint4*)q0;  g0b = *(const uint2*)(q0 + 8);        \
        const f16* q1 = &ctab[a1 * CROWH + 12];                         \
        g1a = *(const uint2*)q1;  g1b = *(const uint2*)(q1 + 4);        \
        g1c = *(const uint2*)(q1 + 8);                                  \
        const f16* q2 = &ctab[a2 * CROWH + 24];                         \
        g2a = *(const uint4*)q2;  g2b = *(const uint2*)(q2 + 8);        \
        const f16* q3 = &ctab[a3 * CROWH + 36];                         \
        g3a = *(const uint2*)q3;  g3b = *(const uint2*)(q3 + 4);        \
        g3c = *(const uint2*)(q3 + 8); }

// gather sum: 18 packed f16 adds -> xg0..5 (12 conv feats)
#define G_SUM                                                           \
    {   f16x2 s0 = bc2(g0a.x) + bc2(g1a.x) + bc2(g2a.x) + bc2(g3a.x);  \
        f16x2 s1 = bc2(g0a.y) + bc2(g1a.y) + bc2(g2a.y) + bc2(g3a.y);  \
        f16x2 s2 = bc2(g0a.z) + bc2(g1b.x) + bc2(g2a.z) + bc2(g3b.x);  \
        f16x2 s3 = bc2(g0a.w) + bc2(g1b.y) + bc2(g2a.w) + bc2(g3b.y);  \
        f16x2 s4 = bc2(g0b.x) + bc2(g1c.x) + bc2(g2b.x) + bc2(g3c.x);  \
        f16x2 s5 = bc2(g0b.y) + bc2(g1c.y) + bc2(g2b.y) + bc2(g3c.y);  \
        xg0 = bcu(s0); xg1 = bcu(s1); xg2 = bcu(s2);                   \
        xg3 = bcu(s3); xg4 = bcu(s4); xg5 = bcu(s5); }

// advance rolling ages by 2 processing steps (direction-dependent)
#define G_ADV                                                           \
    if (fw) { a3 = a1; a2 = a0; a1 = chload(pp + 1); a0 = chload(pp + 2); pp += 2; } \
    else    { a0 = a2; a1 = a3; a2 = chload(pp - 4); a3 = chload(pp - 5); pp -= 2; }

__global__ __launch_bounds__(256, 4) void cnn_lstm_kernel(
    const int* __restrict__ inp, const float* __restrict__ emb,
    const float* __restrict__ k2, const float* __restrict__ k3,
    const float* __restrict__ k4,
    const float* __restrict__ wfw, const float* __restrict__ bfw,
    const float* __restrict__ wbw, const float* __restrict__ bbw,
    float* __restrict__ out)
{
    // ctab[v]: 48 used halves: age d feats at halves [12d .. 12d+12), exact
    // zeros where the kernel tap is out of range. Row SENT all zero.
    __shared__ __align__(16) f16 ctab[(VOCAB + 1) * CROWH];   // 28.8 KB
    // X rows per wave: 32 seqs x [x(12) | h(10) | 1.0 | 0]; row 32 = zero
    // junk-catcher for the g=3 fragment over-read.
    __shared__ __align__(16) f16 xbuf[WAVES][33][XROW];       // 6.3 KB

    const int tid  = threadIdx.x;
    const int lane = tid & 63;
    const int w    = tid >> 6;
    const int g    = lane >> 4;     // k-group
    const int c16  = lane & 15;
    const int p    = lane >> 5;     // parity role (0/1)
    const int s    = lane & 31;     // owned seq within wave

    // ---- build ctab: thread v = tid handles one vocab row ------------------
    {
        float er[EDIM];
        const float4* ep = (const float4*)(emb + tid * EDIM);
        float4 e0 = ep[0], e1 = ep[1], e2 = ep[2], e3 = ep[3];
        er[0] = e0.x; er[1] = e0.y; er[2] = e0.z; er[3] = e0.w;
        er[4] = e1.x; er[5] = e1.y; er[6] = e1.z; er[7] = e1.w;
        er[8] = e2.x; er[9] = e2.y; er[10] = e2.z; er[11] = e2.w;
        er[12] = e3.x; er[13] = e3.y; er[14] = e3.z; er[15] = e3.w;

        unsigned wd[24];
        #pragma unroll
        for (int dlt = 0; dlt < 4; ++dlt) {
            float o[12];
            #pragma unroll
            for (int f = 0; f < 12; ++f) o[f] = 0.0f;
            const int tap2 = 1 - dlt, tap3 = 2 - dlt, tap4 = 3 - dlt;
            if (tap2 >= 0) {
                #pragma unroll
                for (int e = 0; e < EDIM; ++e) {
                    const float x = er[e];
                    #pragma unroll
                    for (int f = 0; f < 3; ++f) o[f] += x * k2[(tap2 * EDIM + e) * 3 + f];
                }
            }
            if (tap3 >= 0) {
                #pragma unroll
                for (int e = 0; e < EDIM; ++e) {
                    const float x = er[e];
                    #pragma unroll
                    for (int f = 0; f < 4; ++f) o[3 + f] += x * k3[(tap3 * EDIM + e) * 4 + f];
                }
            }
            {
                #pragma unroll
                for (int e = 0; e < EDIM; ++e) {
                    const float x = er[e];
                    #pragma unroll
                    for (int f = 0; f < 5; ++f) o[7 + f] += x * k4[(tap4 * EDIM + e) * 5 + f];
                }
            }
            #pragma unroll
            for (int k = 0; k < 6; ++k) wd[6 * dlt + k] = pk(o[2 * k], o[2 * k + 1]);
        }
        uint4* dst = (uint4*)&ctab[tid * CROWH];
        #pragma unroll
        for (int j = 0; j < 6; ++j)
            dst[j] = make_uint4(wd[4 * j], wd[4 * j + 1], wd[4 * j + 2], wd[4 * j + 3]);
    }
    if (tid < 6) ((uint4*)&ctab[SENT * CROWH])[tid] = make_uint4(0, 0, 0, 0);

    // ---- per-wave init ------------------------------------------------------
    const int dir   = blockIdx.x >> 9;             // 1024 blocks: 0..511 fw
    const bool fw   = (dir == 0);
    const int nbase = (blockIdx.x & 511) * 128 + w * 32;
    const int* inp_s = inp + (nbase + s) * SC;
    const float* Wm = fw ? wfw : wbw;
    const float* Bv = fw ? bfw : bbw;

    // A-frags (loaded once): physical gate 16mg+4q+r holds logical part r of
    // quad Lq(mg,q) = {2q, 2q+1, 8+q}; k rows: 0..11 x, 12..21 h, 22 bias.
    f16x8 afr[3];
    {
        const int qg = c16 >> 2, r = c16 & 3;
        #pragma unroll
        for (int mg = 0; mg < 3; ++mg) {
            const int Lq = (mg == 0) ? 2 * qg : (mg == 1) ? (2 * qg + 1) : (8 + qg);
            const bool valid = (Lq < HDIM);
            const int lcol = r * HDIM + Lq;
            #pragma unroll
            for (int i = 0; i < 8; ++i) {
                const int kk = 8 * g + i;
                float val = 0.0f;
                if (valid) {
                    if (kk < 22) val = Wm[kk * 40 + lcol];
                    else if (kk == 22) val = Bv[lcol];
                }
                afr[mg][i] = (f16)val;
            }
        }
    }

    // init own X row h-part (h=0, bias 1.0 at half 22) and the junk row
    if (p == 0) {
        f16* xr = &xbuf[w][s][0];
        *(uint2*)(xr + 12) = make_uint2(0u, 0u);
        *(uint2*)(xr + 16) = make_uint2(0u, 0u);
        *(uint2*)(xr + 20) = make_uint2(0u, pk(1.0f, 0.0f));
    }
    if (lane == 0) {
        uint4* jr = (uint4*)&xbuf[w][32][0];
        jr[0] = make_uint4(0, 0, 0, 0);
        jr[1] = make_uint4(0, 0, 0, 0);
        jr[2] = make_uint4(0, 0, 0, 0);
    }
    __syncthreads();

    auto chload = [&](int q) -> int {
        return ((unsigned)q < (unsigned)SC) ? inp_s[q] : SENT;
    };

    // rolling ages for this lane's NEXT gather target T (first T = parity p);
    // pp = original char position of target T.
    int pp = fw ? p : (SC - 1 - p);
    int a0 = chload(pp), a1 = chload(pp - 1), a2 = chload(pp - 2), a3 = chload(pp - 3);

    unsigned xg0, xg1, xg2, xg3, xg4, xg5;
    uint4 g0a, g2a;
    uint2 g0b, g1a, g1b, g1c, g2b, g3a, g3b, g3c;

    // prologue: parity-0 lanes gather + write x(0)
    if (p == 0) {
        G_ISSUE
        G_SUM
        f16* xr = &xbuf[w][s][0];
        *(uint4*)xr = make_uint4(xg0, xg1, xg2, xg3);
        *(uint2*)(xr + 8) = make_uint2(xg4, xg5);
        G_ADV
    }

    float creg[2][3], hreg[2][3];
    #pragma unroll
    for (int ms = 0; ms < 2; ++ms)
        #pragma unroll
        for (int mg = 0; mg < 3; ++mg) { creg[ms][mg] = 0.0f; hreg[ms][mg] = 0.0f; }

    const f32x4 zero4 = {0.0f, 0.0f, 0.0f, 0.0f};

    #pragma unroll 1
    for (int t = 0; t < SC; ++t) {
        const bool iswriter = (p == (t & 1));

        // 1. writer half: commit x(t) (gathered during iter t-1)
        if (t > 0 && iswriter) {
            f16* xr = &xbuf[w][s][0];
            *(uint4*)xr = make_uint4(xg0, xg1, xg2, xg3);
            *(uint2*)(xr + 8) = make_uint2(xg4, xg5);
        }

        // 2. B-frags (must be issued BEFORE the gathers so MFMA's wait is
        //    lgkmcnt(10), not 0 — LDS completes in order)
        f16x8 bf0 = *(const f16x8*)&xbuf[w][c16][8 * g];
        f16x8 bf1 = *(const f16x8*)&xbuf[w][16 + c16][8 * g];
        __builtin_amdgcn_sched_barrier(0);

        // 3. gather half: issue reads for x(t+1); prefetch next char indices
        const bool dogather = (!iswriter) && (t < SC - 1);
        if (dogather) {
            G_ISSUE
            G_ADV
        }
        __builtin_amdgcn_sched_barrier(0);

        // 4. MFMA: Z^T tiles (waits only on B-frags)
        f32x4 acc[2][3];
        #pragma unroll
        for (int mg = 0; mg < 3; ++mg) {
            acc[0][mg] = __builtin_amdgcn_mfma_f32_16x16x32_f16(afr[mg], bf0, zero4, 0, 0, 0);
            acc[1][mg] = __builtin_amdgcn_mfma_f32_16x16x32_f16(afr[mg], bf1, zero4, 0, 0, 0);
        }
        __builtin_amdgcn_sched_barrier(0);

        // 5. gather half: fold read returns into xg (reads have landed by now)
        if (dogather) {
            G_SUM
        }

        // 6. combine: lane owns quads {2g, 2g+1, 8+g} of seqs {c16, 16+c16}
        #pragma unroll
        for (int ms = 0; ms < 2; ++ms) {
            #pragma unroll
            for (int mg = 0; mg < 3; ++mg) {
                const f32x4 z = acc[ms][mg];
                const float ij = fast_sig(z[0]) * fast_tanh(z[1]);
                const float fg = fast_sig(z[2] + 1.0f);
                const float og = fast_sig(z[3]);
                creg[ms][mg] = fg * creg[ms][mg] + ij;
                hreg[ms][mg] = og * fast_tanh(creg[ms][mg]);
            }
            f16* xr = &xbuf[w][16 * ms + c16][0];
            *(unsigned*)(xr + 12 + 2 * g) = pk(hreg[ms][0], hreg[ms][1]);
            if (g < 2) xr[20 + g] = (f16)hreg[ms][2];
        }
        __builtin_amdgcn_sched_barrier(0);
    }

    // ---- output: quads {2g, 2g+1} paired, {8+g} masked ----------------------
    #pragma unroll
    for (int ms = 0; ms < 2; ++ms) {
        const int n = nbase + 16 * ms + c16;
        float2 hv;
        hv.x = hreg[ms][0];
        hv.y = hreg[ms][1];
        *(float2*)&out[n * (2 * HDIM) + dir * HDIM + 2 * g] = hv;
        if (g < 2) out[n * (2 * HDIM) + dir * HDIM + 8 + g] = hreg[ms][2];
    }
}

extern "C" void kernel_launch(void* const* d_in, const int* in_sizes, int n_in,
                              void* d_out, int out_size, void* d_ws, size_t ws_size,
                              hipStream_t stream) {
    const int*   inp = (const int*)d_in[0];
    const float* emb = (const float*)d_in[1];
    const float* k2  = (const float*)d_in[2];
    const float* k3  = (const float*)d_in[3];
    const float* k4  = (const float*)d_in[4];
    const float* wfw = (const float*)d_in[5];
    const float* bfw = (const float*)d_in[6];
    const float* wbw = (const float*)d_in[7];
    const float* bbw = (const float*)d_in[8];
    float* out = (float*)d_out;

    // 1024 blocks x 256 threads: 32 seqs/wave, 2 lanes (parities) per seq.
    cnn_lstm_kernel<<<dim3(1024), dim3(256), 0, stream>>>(
        inp, emb, k2, k3, k4, wfw, bfw, wbw, bbw, out);
}